// Round 1
// 145.630 us; speedup vs baseline: 1.0150x; 1.0150x over previous
//
#include <hip/hip_runtime.h>
#include <math.h>

// CenterNetDecode fused: heat [8,80,192,192] f32, box [8,4,192,192] f32
// outputs (flat concat): boxes [B,H,W,4], mask [B,H,W], scores [B,H,W], center [B,H,W,2]
//
// Single kernel: block = one row-strip (SS=6 rows) of one batch image, ALL 80
// channels. 8 waves x 10 channels each; wave = full image row (lanes 0..47
// hold float4, cols 4l..4l+3). 3x3 NMS via vertical reg-max + 2 shuffles/row.
// Wave partials -> LDS -> 8-way max -> inline decode. Grid 32x8 = 256 blocks
// = exactly 1 block/CU (no tail). No workspace, no second dispatch.

#define BB 8
#define CC 80
#define HH 192
#define WW 192
#define SS 6                 // rows per block strip  (HH/SS = 32 strips)
#define NPIX (SS*WW)         // 1152 pixels per block
#define NBPIX (BB*HH*WW)     // 294912

__global__ __launch_bounds__(512) void fused_kernel(const float* __restrict__ heat,
                                                    const float* __restrict__ box,
                                                    float* __restrict__ out) {
    const int tid  = threadIdx.x;
    const int lane = tid & 63;
    const int wv   = tid >> 6;        // wave 0..7
    const int yt   = blockIdx.x;      // 0..31
    const int b    = blockIdx.y;      // 0..7
    const int y0   = yt * SS;
    const bool lok = lane < 48;
    const int  col0 = lane * 4;

    __shared__ float red[8][SS][WW];  // 36 KB

    float4 sc[SS];
#pragma unroll
    for (int i = 0; i < SS; ++i) sc[i] = make_float4(0.f, 0.f, 0.f, 0.f);

    const int cbase = wv * 10;        // 8 waves x 10 channels = 80
    const float NI = -INFINITY;

    for (int k = 0; k < 10; ++k) {
        const int c = cbase + k;
        const float* hp = heat + ((size_t)(b * CC + c) * HH) * WW;
        float4 v[SS + 2];
#pragma unroll
        for (int r = 0; r < SS + 2; ++r) {
            const int  row = y0 - 1 + r;
            const bool ok  = lok && ((unsigned)row < HH);
            v[r] = ok ? *reinterpret_cast<const float4*>(hp + row * WW + col0)
                      : make_float4(NI, NI, NI, NI);
        }
#pragma unroll
        for (int i = 0; i < SS; ++i) {
            const float4 a = v[i], m = v[i + 1], d = v[i + 2];
            float4 vm;
            vm.x = fmaxf(fmaxf(a.x, m.x), d.x);
            vm.y = fmaxf(fmaxf(a.y, m.y), d.y);
            vm.z = fmaxf(fmaxf(a.z, m.z), d.z);
            vm.w = fmaxf(fmaxf(a.w, m.w), d.w);

            float L = __shfl_up(vm.w, 1);    // left neighbor's col (4l-1)
            float R = __shfl_down(vm.x, 1);  // right neighbor's col (4l+4)
            if (lane == 0)  L = NI;          // image left edge
            if (lane >= 47) R = NI;          // image right edge / inactive

            float4 hm;
            hm.x = fmaxf(fmaxf(L,    vm.x), vm.y);
            hm.y = fmaxf(fmaxf(vm.x, vm.y), vm.z);
            hm.z = fmaxf(fmaxf(vm.y, vm.z), vm.w);
            hm.w = fmaxf(fmaxf(vm.z, vm.w), R);

            sc[i].x = fmaxf(sc[i].x, (m.x == hm.x) ? m.x : 0.0f);
            sc[i].y = fmaxf(sc[i].y, (m.y == hm.y) ? m.y : 0.0f);
            sc[i].z = fmaxf(sc[i].z, (m.z == hm.z) ? m.z : 0.0f);
            sc[i].w = fmaxf(sc[i].w, (m.w == hm.w) ? m.w : 0.0f);
        }
    }

    // ---- decode prefetch: issue box loads BEFORE the barrier (latency hides
    //      under barrier + LDS reduce). Strip is linear: pix = pixbase + idx.
    const int    pixbase = (b * HH + y0) * WW;
    const float* bp0     = box + (size_t)b * 4 * HH * WW + (size_t)y0 * WW;
    float pdx[3], pdy[3], pw[3], ph[3];
#pragma unroll
    for (int kk = 0; kk < 3; ++kk) {
        const int idx = kk * 512 + tid;
        if (idx < NPIX) {
            pdx[kk] = bp0[idx];
            pdy[kk] = bp0[idx + (size_t)HH * WW];
            pw[kk]  = bp0[idx + (size_t)2 * HH * WW];
            ph[kk]  = bp0[idx + (size_t)3 * HH * WW];
        }
    }

    if (lok) {
#pragma unroll
        for (int i = 0; i < SS; ++i)
            *reinterpret_cast<float4*>(&red[wv][i][col0]) = sc[i];
    }
    __syncthreads();

    float* boxes  = out;
    float* maskp  = out + (size_t)4 * NBPIX;
    float* scorep = out + (size_t)5 * NBPIX;
    float* ctr    = out + (size_t)6 * NBPIX;

    const float* rf = &red[0][0][0];      // linear view: rf[w*NPIX + idx]

#pragma unroll
    for (int kk = 0; kk < 3; ++kk) {
        const int idx = kk * 512 + tid;
        if (idx < NPIX) {
            const int row = idx / WW;
            const int x   = idx - row * WW;
            const int y   = y0 + row;

            float s = rf[idx];
#pragma unroll
            for (int w = 1; w < 8; ++w) s = fmaxf(s, rf[w * NPIX + idx]);
            const bool m = s > 0.7f;

            const float cx = ((float)x + pdx[kk]) * 4.0f;
            const float cy = ((float)y + pdy[kk]) * 4.0f;
            const float w4 = pw[kk] * 4.0f;
            const float h4 = ph[kk] * 4.0f;
            const float lim = 768.0f;
            const float x1 = fminf(fmaxf(cx - w4 * 0.5f, 0.0f), lim);
            const float y1 = fminf(fmaxf(cy - h4 * 0.5f, 0.0f), lim);
            const float x2 = fminf(fmaxf(cx + w4 * 0.5f, 0.0f), lim);
            const float y2 = fminf(fmaxf(cy + h4 * 0.5f, 0.0f), lim);

            const int pix = pixbase + idx;

            float4 bo;
            bo.x = m ? x1 : 0.0f;
            bo.y = m ? y1 : 0.0f;
            bo.z = m ? (x2 - x1) : 0.0f;
            bo.w = m ? (y2 - y1) : 0.0f;
            reinterpret_cast<float4*>(boxes)[pix] = bo;

            maskp[pix]  = m ? 1.0f : 0.0f;
            scorep[pix] = m ? s : 0.0f;

            float2 cc;
            cc.x = m ? cx : 0.0f;
            cc.y = m ? cy : 0.0f;
            reinterpret_cast<float2*>(ctr)[pix] = cc;
        }
    }
}

extern "C" void kernel_launch(void* const* d_in, const int* in_sizes, int n_in,
                              void* d_out, int out_size, void* d_ws, size_t ws_size,
                              hipStream_t stream) {
    const float* heat = (const float*)d_in[0];
    const float* box  = (const float*)d_in[1];
    float* out = (float*)d_out;

    dim3 g(HH / SS, BB);              // 32 x 8 = 256 blocks, 1 per CU
    fused_kernel<<<g, 512, 0, stream>>>(heat, box, out);
}